// Round 6
// baseline (275.831 us; speedup 1.0000x reference)
//
#include <hip/hip_runtime.h>
#include <math.h>

#define CI 12
#define NHID 15
#define NBLK 6144                 // 8*3*16*16 image blocks of 32x32
#define NPIX (NBLK * 1024)

typedef float  f32x4 __attribute__((ext_vector_type(4)));
typedef int    i32x4 __attribute__((ext_vector_type(4)));
typedef short  s16x8 __attribute__((ext_vector_type(8)));

// f32 -> bf16 trunc pack via byte-perm: dst = hi16(hi):hi16(lo)
static __device__ __forceinline__ int bfpack(float lo, float hi) {
    return (int)__builtin_amdgcn_perm(__float_as_uint(hi), __float_as_uint(lo),
                                      0x07060302u);
}
// f32 -> bf16 RNE (weights, cold path)
static __device__ __forceinline__ unsigned bfrne(float x) {
    unsigned u = __float_as_uint(x);
    u += 0x7FFFu + ((u >> 16) & 1u);
    return u >> 16;
}
static __device__ __forceinline__ int bfpack_rne(float lo, float hi) {
    return (int)((bfrne(hi) << 16) | bfrne(lo));
}
static __device__ __forceinline__ float leaky(float x) {
    return fmaxf(x, 0.01f * x);
}
static __device__ __forceinline__ f32x4 mfma16(i32x4 a, i32x4 b, f32x4 c) {
    return __builtin_amdgcn_mfma_f32_16x16x32_bf16(
        __builtin_bit_cast(s16x8, a), __builtin_bit_cast(s16x8, b), c, 0, 0, 0);
}

// Sparse-K layout (validated R4/R5): channel c=4q+r at k-slot 8q+r (q=0..2);
// bias at k=4; all other k-slots carry zero weights, so the MFMA C-layout
// output IS the next layer's B-frag. No cross-lane moves.
// R6: weights live in LDS (ds_read_b128 per layer) so the allocator never
// touches AGPRs (no v_accvgpr traffic) and 512-thr/2-image-block workgroups
// reach 32 waves/CU.
__global__ __launch_bounds__(512, 8) void codec_main(
    const float* __restrict__ x,
    const float* __restrict__ Wh,   // [15][12][12]
    const float* __restrict__ bh,   // [15][12]
    const float* __restrict__ Wo,   // [12]
    const float* __restrict__ bo,   // [1]
    float* __restrict__ out,        // [1 + NPIX]
    float* __restrict__ loss_acc)   // [1] pre-zeroed
{
    __shared__ float tile2[2 * 36 * 37]; // two 32x32 blocks + 2-halo, +1 pad
    __shared__ i32x4 ldsW[16 * 64];      // A-frags: [layer(15)+head][lane]
    __shared__ float wsum[8];

    const int tid  = threadIdx.x;   // 0..511
    const int lane = tid & 63;
    const int sub  = tid >> 8;      // image-block within workgroup (0/1)
    const int wv4  = (tid >> 6) & 3;// wave within image-block (0..3)
    const int t    = lane & 15;
    const int q    = lane >> 4;

    // ---- zero both padded tiles ----
    for (int i = tid; i < 2 * 36 * 37; i += 512) tile2[i] = 0.0f;
    __syncthreads();

    // ---- stage pixels (both tiles) + weights (cooperative) ----
    {
        const int tloc = tid & 255;
        const int col  = tloc & 31;
        const int r0   = tloc >> 5;
        const int n2   = blockIdx.x * 2 + sub;
        const int bc   = n2 >> 8;
        const int blk  = n2 & 255;
        const int by   = blk >> 4;
        const int bx   = blk & 15;
        #pragma unroll
        for (int p = 0; p < 4; ++p) {
            const int row = r0 + 8 * p;
            tile2[sub * 1332 + (row + 2) * 37 + col + 2] =
                x[((size_t)bc * 512 + (size_t)(by * 32 + row)) * 512
                  + (size_t)(bx * 32 + col)];
        }
        // weight A-frags: entry i -> layer l=i>>6 (15 = head), target lane i&63
        for (int i = tid; i < 16 * 64; i += 512) {
            const int l  = i >> 6;
            const int ln = i & 63;
            const int qq = ln >> 4;
            const int tt = ln & 15;
            float4 w = {0.f, 0.f, 0.f, 0.f};
            float  b = 0.f;
            if (l < NHID) {
                if (tt < CI && qq < 3) {
                    w = *(const float4*)(Wh + l * (CI * CI) + tt * CI + 4 * qq);
                    if (qq == 0) b = bh[l * CI + tt];
                }
            } else {                 // head: row m=0 only
                if (tt == 0 && qq < 3) {
                    w = *(const float4*)(Wo + 4 * qq);
                    if (qq == 0) b = bo[0];
                }
            }
            ldsW[i] = (i32x4){ bfpack_rne(w.x, w.y), bfpack_rne(w.z, w.w),
                               bfpack_rne(b, 0.f), 0 };
        }
    }
    __syncthreads();

    // ---- per-lane feature offsets (elements): channel c=4q+r at (dy,dx) ----
    // r0:{-76,-72,-36,0} r1:{-75,-39,-35,0} r2:{-74,-38,-2,0} r3:{-73,-37,-1,0}
    const int sh8  = q * 8;
    const int off0 = (int)(signed char)((0x00DCB8B4u >> sh8) & 0xFFu);
    const int off1 = (int)(signed char)((0x00DDD9B5u >> sh8) & 0xFFu);
    const int off2 = (int)(signed char)((0x00FEDAB6u >> sh8) & 0xFFu);
    const int off3 = (int)(signed char)((0x00FFDBB7u >> sh8) & 0xFFu);

    const float* tp = tile2 + sub * 1332;
    const int base  = (wv4 * 8 + 2) * 37 + (t + 2);
    int e0 = base + off0;
    int e1 = base + off1;
    int e2 = base + off2;
    int e3 = base + off3;
    int ev = base;

    const int   biasreg = (q == 0) ? 0x00003F80 : 0;  // k=4 slot = bf16(1.0)
    const f32x4 zero4   = {0.f, 0.f, 0.f, 0.f};
    const int   n2      = blockIdx.x * 2 + sub;
    float*      outp    = out + 1 + (size_t)n2 * 1024;

    float d2 = 0.0f;
    #pragma unroll 1
    for (int yi = 0; yi < 8; ++yi) {
        const float fA0 = tp[e0], fB0 = tp[e0 + 16];
        const float fA1 = tp[e1], fB1 = tp[e1 + 16];
        const float fA2 = tp[e2], fB2 = tp[e2 + 16];
        const float fA3 = tp[e3], fB3 = tp[e3 + 16];
        const float vA  = tp[ev], vB  = tp[ev + 16];

        i32x4 BA = (i32x4){ bfpack(fA0, fA1), bfpack(fA2, fA3), biasreg, 0 };
        i32x4 BB = (i32x4){ bfpack(fB0, fB1), bfpack(fB2, fB3), biasreg, 0 };

        i32x4 w = ldsW[lane];                      // layer 0
        f32x4 aA, aB;
        #pragma unroll
        for (int l = 0; l < NHID; ++l) {
            const i32x4 wn = ldsW[(l + 1) * 64 + lane];   // next (15 = head)
            aA = mfma16(w, BA, zero4);
            aB = mfma16(w, BB, zero4);
            BA[0] = bfpack(leaky(aA[0]), leaky(aA[1]));
            BA[1] = bfpack(leaky(aA[2]), leaky(aA[3]));
            BB[0] = bfpack(leaky(aB[0]), leaky(aB[1]));
            BB[1] = bfpack(leaky(aB[2]), leaky(aB[3]));
            w = wn;
        }
        aA = mfma16(w, BA, zero4);                 // head
        aB = mfma16(w, BB, zero4);

        if (lane < 16) {                           // row 0 of D = prediction
            const float pA = fminf(fmaxf(aA[0], -1.0f), 1.0f);
            const float uA = vA - pA + 1.0f;
            const float dA = uA - ((uA < 2.0f) ? 1.0f : 3.0f); // fmod(u,2)-1
            const float pB = fminf(fmaxf(aB[0], -1.0f), 1.0f);
            const float uB = vB - pB + 1.0f;
            const float dB = uB - ((uB < 2.0f) ? 1.0f : 3.0f);
            const int y = wv4 * 8 + yi;
            outp[y * 32 + t]      = dA;
            outp[y * 32 + 16 + t] = dB;
            d2 = fmaf(dA, dA, fmaf(dB, dB, d2));
        }
        e0 += 37; e1 += 37; e2 += 37; e3 += 37; ev += 37;
    }

    // ---- loss reduction (d2 nonzero only in lanes 0..15 of each wave) ----
    #pragma unroll
    for (int off = 8; off > 0; off >>= 1) d2 += __shfl_down(d2, off, 64);
    if (lane == 0) wsum[tid >> 6] = d2;
    __syncthreads();
    if (tid == 0) {
        float s = 0.f;
        #pragma unroll
        for (int i = 0; i < 8; ++i) s += wsum[i];
        atomicAdd(loss_acc, s);
    }
}

__global__ void codec_loss(const float* __restrict__ acc, float* __restrict__ out)
{
    out[0] = 255.0f * sqrtf(acc[0] / (float)NPIX);
}

extern "C" void kernel_launch(void* const* d_in, const int* in_sizes, int n_in,
                              void* d_out, int out_size, void* d_ws, size_t ws_size,
                              hipStream_t stream)
{
    const float* x  = (const float*)d_in[0];
    const float* Wh = (const float*)d_in[1];
    const float* bh = (const float*)d_in[2];
    const float* Wo = (const float*)d_in[3];
    const float* bo = (const float*)d_in[4];
    float* out = (float*)d_out;
    float* acc = (float*)d_ws;

    hipMemsetAsync(acc, 0, sizeof(float), stream);   // graph-capture safe
    codec_main<<<NBLK / 2, 512, 0, stream>>>(x, Wh, bh, Wo, bo, out, acc);
    codec_loss<<<1, 1, 0, stream>>>(acc, out);
}

// Round 7
// 219.613 us; speedup vs baseline: 1.2560x; 1.2560x over previous
//
#include <hip/hip_runtime.h>
#include <math.h>

#define CI 12
#define NHID 15
#define NBLK 6144                 // 8*3*16*16 image blocks of 32x32
#define NPIX (NBLK * 1024)

typedef int i32x4 __attribute__((ext_vector_type(4)));

// f32 -> bf16 trunc pack (cold path / feature init)
static __device__ __forceinline__ int bfpack(float lo, float hi) {
    return (int)__builtin_amdgcn_perm(__float_as_uint(hi), __float_as_uint(lo),
                                      0x07060302u);
}
// f32 -> bf16 RNE (weights)
static __device__ __forceinline__ unsigned bfrne(float x) {
    unsigned u = __float_as_uint(x);
    u += 0x7FFFu + ((u >> 16) & 1u);
    return u >> 16;
}
static __device__ __forceinline__ int bfpack_rne(float lo, float hi) {
    return (int)((bfrne(hi) << 16) | bfrne(lo));
}

// ---- hand-scheduled hot-loop asm ------------------------------------------
// Fixed VGPRs (clobbered): Z=v[32:35], BA=v[36:39], BB=v[40:43], BC=v[44:47],
// BD=v[48:51], DA=v[52:55], DB=v[56:59], DC=v[60:63], DD=v[64:67], tmp v68/v69.
// Weights: 16 AGPR quads via operands. leaky = max(x, 0.01x); pack = v_perm.
// Hazard spacing by construction: every MFMA D is first read >=44 cyc after
// issue; every B-quad write is >=10 inst before its MFMA read.
#define LKA \
  "v_mul_f32 v68, 0x3c23d70a, v52\n" \
  "v_mul_f32 v69, 0x3c23d70a, v53\n" \
  "v_max_f32 v52, v52, v68\n" \
  "v_max_f32 v53, v53, v69\n" \
  "v_perm_b32 v36, v53, v52, s20\n" \
  "v_mul_f32 v68, 0x3c23d70a, v54\n" \
  "v_mul_f32 v69, 0x3c23d70a, v55\n" \
  "v_max_f32 v54, v54, v68\n" \
  "v_max_f32 v55, v55, v69\n" \
  "v_perm_b32 v37, v55, v54, s20\n"
#define LKB \
  "v_mul_f32 v68, 0x3c23d70a, v56\n" \
  "v_mul_f32 v69, 0x3c23d70a, v57\n" \
  "v_max_f32 v56, v56, v68\n" \
  "v_max_f32 v57, v57, v69\n" \
  "v_perm_b32 v40, v57, v56, s20\n" \
  "v_mul_f32 v68, 0x3c23d70a, v58\n" \
  "v_mul_f32 v69, 0x3c23d70a, v59\n" \
  "v_max_f32 v58, v58, v68\n" \
  "v_max_f32 v59, v59, v69\n" \
  "v_perm_b32 v41, v59, v58, s20\n"
#define LKC \
  "v_mul_f32 v68, 0x3c23d70a, v60\n" \
  "v_mul_f32 v69, 0x3c23d70a, v61\n" \
  "v_max_f32 v60, v60, v68\n" \
  "v_max_f32 v61, v61, v69\n" \
  "v_perm_b32 v44, v61, v60, s20\n" \
  "v_mul_f32 v68, 0x3c23d70a, v62\n" \
  "v_mul_f32 v69, 0x3c23d70a, v63\n" \
  "v_max_f32 v62, v62, v68\n" \
  "v_max_f32 v63, v63, v69\n" \
  "v_perm_b32 v45, v63, v62, s20\n"
#define LKD \
  "v_mul_f32 v68, 0x3c23d70a, v64\n" \
  "v_mul_f32 v69, 0x3c23d70a, v65\n" \
  "v_max_f32 v64, v64, v68\n" \
  "v_max_f32 v65, v65, v69\n" \
  "v_perm_b32 v48, v65, v64, s20\n" \
  "v_mul_f32 v68, 0x3c23d70a, v66\n" \
  "v_mul_f32 v69, 0x3c23d70a, v67\n" \
  "v_max_f32 v66, v66, v68\n" \
  "v_max_f32 v67, v67, v69\n" \
  "v_perm_b32 v49, v67, v66, s20\n"

#define MFA(w) "v_mfma_f32_16x16x32_bf16 v[52:55], %[" w "], v[36:39], v[32:35]\n"
#define MFB(w) "v_mfma_f32_16x16x32_bf16 v[56:59], %[" w "], v[40:43], v[32:35]\n"
#define MFC(w) "v_mfma_f32_16x16x32_bf16 v[60:63], %[" w "], v[44:47], v[32:35]\n"
#define MFD(w) "v_mfma_f32_16x16x32_bf16 v[64:67], %[" w "], v[48:51], v[32:35]\n"

#define LAYER(w) LKA LKB MFA(w) LKC MFB(w) LKD MFC(w) "s_nop 1\n" MFD(w)

__global__ __launch_bounds__(256, 3) void codec_main(
    const float* __restrict__ x,
    const float* __restrict__ Wh,   // [15][12][12]
    const float* __restrict__ bh,   // [15][12]
    const float* __restrict__ Wo,   // [12]
    const float* __restrict__ bo,   // [1]
    float* __restrict__ out,        // [1 + NPIX]
    float* __restrict__ loss_acc)   // [1] pre-zeroed
{
    __shared__ float tile[36 * 37]; // 32x32 + 2-halo, +1 col pad
    __shared__ float stage[4][256]; // per-wave delta staging
    __shared__ float wsum[4];

    const int n    = blockIdx.x;
    const int tid  = threadIdx.x;   // 0..255
    const int lane = tid & 63;
    const int wv   = tid >> 6;      // wave 0..3
    const int t    = lane & 15;
    const int q    = lane >> 4;

    // ---- stage image block into LDS (zero halo) ----
    {
        const int col = tid & 31;
        const int r0  = tid >> 5;
        #pragma unroll
        for (int i = 0; i < 6; ++i) {
            int idx = tid + i * 256;
            if (idx < 36 * 37) tile[idx] = 0.0f;
        }
        __syncthreads();
        const int bc  = n >> 8;
        const int blk = n & 255;
        const int by  = blk >> 4;
        const int bx  = blk & 15;
        #pragma unroll
        for (int p = 0; p < 4; ++p) {
            const int row = r0 + 8 * p;
            tile[(row + 2) * 37 + col + 2] =
                x[((size_t)bc * 512 + (size_t)(by * 32 + row)) * 512
                  + (size_t)(bx * 32 + col)];
        }
        __syncthreads();
    }

    // ---- weight A-frags (sparse-K, proven R4): lane 16q+t = A[m=t][k=8q+j]
    i32x4 wq[16];
    const bool wok = (t < CI) && (q < 3);
    #pragma unroll
    for (int l = 0; l < NHID; ++l) {
        float4 w = {0.f, 0.f, 0.f, 0.f};
        float  b = 0.f;
        if (wok) w = *(const float4*)(Wh + l * (CI * CI) + t * CI + 4 * q);
        if (wok && q == 0) b = bh[l * CI + t];
        wq[l] = (i32x4){ bfpack_rne(w.x, w.y), bfpack_rne(w.z, w.w),
                         bfpack_rne(b, 0.f), 0 };
    }
    {
        float4 w = {0.f, 0.f, 0.f, 0.f};
        float  b = 0.f;
        if (t == 0 && q < 3) w = *(const float4*)(Wo + 4 * q);
        if (t == 0 && q == 0) b = bo[0];
        wq[15] = (i32x4){ bfpack_rne(w.x, w.y), bfpack_rne(w.z, w.w),
                          bfpack_rne(b, 0.f), 0 };
    }

    // ---- per-lane feature offsets (elements): channel c=4q+r at (dy,dx) ----
    const int sh8  = q * 8;
    const int off0 = (int)(signed char)((0x00DCB8B4u >> sh8) & 0xFFu);
    const int off1 = (int)(signed char)((0x00DDD9B5u >> sh8) & 0xFFu);
    const int off2 = (int)(signed char)((0x00FEDAB6u >> sh8) & 0xFFu);
    const int off3 = (int)(signed char)((0x00FFDBB7u >> sh8) & 0xFFu);

    const int biasreg = (q == 0) ? 0x00003F80 : 0;   // k=4 slot = bf16(1.0)
    int e = (wv * 8 + 2) * 37 + (t + 2);             // row 8wv, half 0

    float d2 = 0.0f;
    #pragma unroll 1
    for (int yi = 0; yi < 4; ++yi) {
        // chains: A=(row r,half0) B=(r,half1) C=(r+1,half0) D=(r+1,half1)
        const int faA0 = bfpack(tile[e + off0],      tile[e + off1]);
        const int faA1 = bfpack(tile[e + off2],      tile[e + off3]);
        const int fbA0 = bfpack(tile[e + off0 + 16], tile[e + off1 + 16]);
        const int fbA1 = bfpack(tile[e + off2 + 16], tile[e + off3 + 16]);
        const int fcA0 = bfpack(tile[e + off0 + 37], tile[e + off1 + 37]);
        const int fcA1 = bfpack(tile[e + off2 + 37], tile[e + off3 + 37]);
        const int fdA0 = bfpack(tile[e + off0 + 53], tile[e + off1 + 53]);
        const int fdA1 = bfpack(tile[e + off2 + 53], tile[e + off3 + 53]);
        const float vA = tile[e], vB = tile[e + 16];
        const float vC = tile[e + 37], vD = tile[e + 53];

        float pA, pB, pC, pD;
        asm volatile(
            "s_mov_b32 s20, 0x07060302\n"
            "v_mov_b32 v32, 0\n" "v_mov_b32 v33, 0\n"
            "v_mov_b32 v34, 0\n" "v_mov_b32 v35, 0\n"
            "v_mov_b32 v36, %[fa0]\n" "v_mov_b32 v37, %[fa1]\n"
            "v_mov_b32 v38, %[bias]\n" "v_mov_b32 v39, 0\n"
            "v_mov_b32 v40, %[fb0]\n" "v_mov_b32 v41, %[fb1]\n"
            "v_mov_b32 v42, %[bias]\n" "v_mov_b32 v43, 0\n"
            "v_mov_b32 v44, %[fc0]\n" "v_mov_b32 v45, %[fc1]\n"
            "v_mov_b32 v46, %[bias]\n" "v_mov_b32 v47, 0\n"
            "v_mov_b32 v48, %[fd0]\n" "v_mov_b32 v49, %[fd1]\n"
            "v_mov_b32 v50, %[bias]\n" "v_mov_b32 v51, 0\n"
            MFA("w0") MFB("w0") MFC("w0") MFD("w0")
            "s_nop 7\n" "s_nop 7\n" "s_nop 7\n"
            LAYER("w1")  LAYER("w2")  LAYER("w3")  LAYER("w4")
            LAYER("w5")  LAYER("w6")  LAYER("w7")  LAYER("w8")
            LAYER("w9")  LAYER("w10") LAYER("w11") LAYER("w12")
            LAYER("w13") LAYER("w14") LAYER("w15")
            "v_mov_b32 %[pA], v52\n"
            "v_mov_b32 %[pB], v56\n"
            "s_nop 7\n" "s_nop 7\n"
            "v_mov_b32 %[pC], v60\n"
            "s_nop 3\n"
            "v_mov_b32 %[pD], v64\n"
            : [pA] "=v"(pA), [pB] "=v"(pB), [pC] "=v"(pC), [pD] "=v"(pD)
            : [w0] "a"(wq[0]),  [w1] "a"(wq[1]),  [w2] "a"(wq[2]),
              [w3] "a"(wq[3]),  [w4] "a"(wq[4]),  [w5] "a"(wq[5]),
              [w6] "a"(wq[6]),  [w7] "a"(wq[7]),  [w8] "a"(wq[8]),
              [w9] "a"(wq[9]),  [w10] "a"(wq[10]), [w11] "a"(wq[11]),
              [w12] "a"(wq[12]), [w13] "a"(wq[13]), [w14] "a"(wq[14]),
              [w15] "a"(wq[15]),
              [fa0] "v"(faA0), [fa1] "v"(faA1), [fb0] "v"(fbA0), [fb1] "v"(fbA1),
              [fc0] "v"(fcA0), [fc1] "v"(fcA1), [fd0] "v"(fdA0), [fd1] "v"(fdA1),
              [bias] "v"(biasreg)
            : "s20",
              "v32","v33","v34","v35","v36","v37","v38","v39",
              "v40","v41","v42","v43","v44","v45","v46","v47",
              "v48","v49","v50","v51","v52","v53","v54","v55",
              "v56","v57","v58","v59","v60","v61","v62","v63",
              "v64","v65","v66","v67","v68","v69");

        if (lane < 16) {                   // D row 0 = prediction, lanes 0..15
            const float qA = fminf(fmaxf(pA, -1.0f), 1.0f);
            const float uA = vA - qA + 1.0f;
            const float dA = uA - ((uA < 2.0f) ? 1.0f : 3.0f); // fmod(u,2)-1
            const float qB = fminf(fmaxf(pB, -1.0f), 1.0f);
            const float uB = vB - qB + 1.0f;
            const float dB = uB - ((uB < 2.0f) ? 1.0f : 3.0f);
            const float qC = fminf(fmaxf(pC, -1.0f), 1.0f);
            const float uC = vC - qC + 1.0f;
            const float dC = uC - ((uC < 2.0f) ? 1.0f : 3.0f);
            const float qD = fminf(fmaxf(pD, -1.0f), 1.0f);
            const float uD = vD - qD + 1.0f;
            const float dD = uD - ((uD < 2.0f) ? 1.0f : 3.0f);
            const int r = 2 * yi;
            stage[wv][r * 32 + t]            = dA;
            stage[wv][r * 32 + 16 + t]       = dB;
            stage[wv][(r + 1) * 32 + t]      = dC;
            stage[wv][(r + 1) * 32 + 16 + t] = dD;
            d2 = fmaf(dA, dA, fmaf(dB, dB, fmaf(dC, dC, fmaf(dD, dD, d2))));
        }
        e += 74;                            // two rows
    }

    // ---- coalesced delta store: wave's 256 floats = rows [8wv, 8wv+8) ----
    float* outp = out + 1 + (size_t)n * 1024 + wv * 256;
    #pragma unroll
    for (int j = 0; j < 4; ++j)
        outp[j * 64 + lane] = stage[wv][j * 64 + lane];

    // ---- loss reduction (d2 nonzero only in lanes 0..15) ----
    #pragma unroll
    for (int off = 8; off > 0; off >>= 1) d2 += __shfl_down(d2, off, 64);
    if (lane == 0) wsum[wv] = d2;
    __syncthreads();
    if (tid == 0) atomicAdd(loss_acc, wsum[0] + wsum[1] + wsum[2] + wsum[3]);
}

__global__ void codec_loss(const float* __restrict__ acc, float* __restrict__ out)
{
    out[0] = 255.0f * sqrtf(acc[0] / (float)NPIX);
}

extern "C" void kernel_launch(void* const* d_in, const int* in_sizes, int n_in,
                              void* d_out, int out_size, void* d_ws, size_t ws_size,
                              hipStream_t stream)
{
    const float* x  = (const float*)d_in[0];
    const float* Wh = (const float*)d_in[1];
    const float* bh = (const float*)d_in[2];
    const float* Wo = (const float*)d_in[3];
    const float* bo = (const float*)d_in[4];
    float* out = (float*)d_out;
    float* acc = (float*)d_ws;

    hipMemsetAsync(acc, 0, sizeof(float), stream);   // graph-capture safe
    codec_main<<<NBLK, 256, 0, stream>>>(x, Wh, bh, Wo, bo, out, acc);
    codec_loss<<<1, 1, 0, stream>>>(acc, out);
}